// Round 6
// baseline (357.563 us; speedup 1.0000x reference)
//
#include <hip/hip_runtime.h>

#define F_IN 128
#define F_ALL 128
#define F_HOP 64

#define RPB_BITS 9
#define RPB 512            // rows per bucket
#define KB_MAX 256         // max buckets (N <= 131072)
#define NBLK_HIST 256      // blocks for hist kernel

typedef unsigned int uint;
typedef unsigned short ushort;
typedef __attribute__((ext_vector_type(8))) short short8v;
typedef __attribute__((ext_vector_type(4))) float float4v;

// ---------------------------------------------------------------- helpers
__device__ __forceinline__ uint pack_bf16(float lo, float hi) {
    uint ul = __float_as_uint(lo), uh = __float_as_uint(hi);
    ul += 0x7FFFu + ((ul >> 16) & 1u);
    uh += 0x7FFFu + ((uh >> 16) & 1u);
    return (ul >> 16) | (uh & 0xFFFF0000u);
}
__device__ __forceinline__ float bf_lo(uint h) { return __uint_as_float(h << 16); }
__device__ __forceinline__ float bf_hi(uint h) { return __uint_as_float(h & 0xFFFF0000u); }
__device__ __forceinline__ ushort to_bf16(float x) {
    uint u = __float_as_uint(x);
    u += 0x7FFFu + ((u >> 16) & 1u);
    return (ushort)(u >> 16);
}

// ---------------------------------------------------------------- MFMA GEMM + bf16 pack
__global__ __launch_bounds__(256) void gemm_mfma_kernel(
    const float* __restrict__ x, const float* __restrict__ W0,
    const float* __restrict__ W1, uint* __restrict__ H2, int N) {
    __shared__ ushort Wlds[16384];    // 4*8*64 fragments * 8 bf16 = 32 KB

    {
        const int t = threadIdx.x;
        #pragma unroll
        for (int i = 0; i < 8; ++i) {
            const int e    = t + 256 * i;
            const int lane = e & 63;
            const int tile = e >> 6;
            const int kt   = tile >> 3;
            const int nt   = tile & 7;
            const int k0   = kt * 32 + (lane >> 4) * 8;
            const int n    = nt * 16 + (lane & 15);
            const float* src = (n < 64) ? (W0 + n) : (W1 + (n - 64));
            float v[8];
            #pragma unroll
            for (int j = 0; j < 8; ++j) v[j] = src[(size_t)(k0 + j) * F_HOP];
            uint4 o;
            o.x = pack_bf16(v[0], v[1]);
            o.y = pack_bf16(v[2], v[3]);
            o.z = pack_bf16(v[4], v[5]);
            o.w = pack_bf16(v[6], v[7]);
            *((uint4*)Wlds + e) = o;
        }
    }
    __syncthreads();

    const int wv   = threadIdx.x >> 6;
    const int lane = threadIdx.x & 63;
    const int rbase = blockIdx.x * 64 + wv * 16;
    if (rbase >= N) return;

    const int m    = lane & 15;
    const int quad = lane >> 4;
    const float* xrow = x + (size_t)(rbase + m) * F_IN + quad * 8;

    float4v acc[8];
    #pragma unroll
    for (int t = 0; t < 8; ++t) acc[t] = (float4v){0.f, 0.f, 0.f, 0.f};

    #pragma unroll
    for (int kt = 0; kt < 4; ++kt) {
        const float4 xa = *(const float4*)(xrow + kt * 32);
        const float4 xb = *(const float4*)(xrow + kt * 32 + 4);
        union { uint4 u; short8v s; } av;
        av.u.x = pack_bf16(xa.x, xa.y);
        av.u.y = pack_bf16(xa.z, xa.w);
        av.u.z = pack_bf16(xb.x, xb.y);
        av.u.w = pack_bf16(xb.z, xb.w);
        #pragma unroll
        for (int nt = 0; nt < 8; ++nt) {
            union { uint4 u; short8v s; } bv;
            bv.u = *((const uint4*)Wlds + (kt * 8 + nt) * 64 + lane);
            acc[nt] = __builtin_amdgcn_mfma_f32_16x16x32_bf16(av.s, bv.s, acc[nt], 0, 0, 0);
        }
    }

    #pragma unroll
    for (int t = 0; t < 4; ++t) {
        #pragma unroll
        for (int i = 0; i < 4; ++i) {
            const int r = rbase + quad * 4 + i;
            H2[(size_t)r * F_HOP + t * 16 + m] = pack_bf16(acc[t][i], acc[t + 4][i]);
        }
    }
}

// ---------------------------------------------------------------- CSR build, stage 1: bucket histogram
__global__ __launch_bounds__(256) void bucket_hist_kernel(
    const int* __restrict__ ei, int* __restrict__ bhist, int E, int K) {
    __shared__ int h[KB_MAX];
    for (int i = threadIdx.x; i < K; i += 256) h[i] = 0;
    __syncthreads();
    const int chunk = (E + NBLK_HIST - 1) / NBLK_HIST;
    const int s = blockIdx.x * chunk;
    const int e = min(s + chunk, E);
    for (int j = s + threadIdx.x; j < e; j += 256)
        atomicAdd(&h[ei[j] >> RPB_BITS], 1);
    __syncthreads();
    for (int i = threadIdx.x; i < K; i += 256)
        bhist[blockIdx.x * KB_MAX + i] = h[i];
}

// ---------------------------------------------------------------- stage 2: scan bucket totals (1 block)
// gnext cursors padded to one per 64 B line (stride 16 ints).
__global__ __launch_bounds__(256) void bucket_scan_kernel(
    const int* __restrict__ bhist, int* __restrict__ bbase,
    int* __restrict__ gnext, int* __restrict__ rowptr, int E, int K, int N) {
    __shared__ int wsum[4];
    const int t = threadIdx.x;
    int s = 0;
    if (t < K)
        for (int i = 0; i < NBLK_HIST; ++i) s += bhist[i * KB_MAX + t];
    int v = s;
    #pragma unroll
    for (int d = 1; d < 64; d <<= 1) {
        int u = __shfl_up(v, (unsigned)d, 64);
        if ((t & 63) >= d) v += u;
    }
    if ((t & 63) == 63) wsum[t >> 6] = v;
    __syncthreads();
    int off = 0;
    #pragma unroll
    for (int i = 0; i < 4; ++i) if (i < (t >> 6)) off += wsum[i];
    const int excl = off + v - s;
    if (t < K) { bbase[t] = excl; gnext[t * 16] = excl; }
    if (t == 0) { bbase[K] = E; rowptr[N] = E; }
}

// ---------------------------------------------------------------- stage 3: direct bucket append
// 196 cursors -> active write frontier = 196 lines (12.5 KB); lines fill all 8
// slots quickly and evict full (write amp ~1x, unlike per-row cursors).
// payload: word0 = col | (r_local << 17), word1 = val fp32
__global__ __launch_bounds__(256) void append_kernel(
    const int* __restrict__ ei, const float* __restrict__ ea,
    int* __restrict__ gnext, int2* __restrict__ gbuf, int E) {
    const int j = blockIdx.x * 256 + threadIdx.x;
    if (j >= E) return;
    const int r = ei[j];
    const int c = ei[E + j];
    const int b = r >> RPB_BITS;
    const int gp = atomicAdd(&gnext[b * 16], 1);
    gbuf[gp] = make_int2(c | ((r & (RPB - 1)) << 17), __float_as_int(ea[j]));
}

// ---------------------------------------------------------------- stage 4: per-bucket sort
__global__ __launch_bounds__(256) void sort_kernel(
    const int* __restrict__ bbase, const int2* __restrict__ gbuf,
    int2* __restrict__ ecv, int* __restrict__ rowptr, int N) {
    __shared__ int cnt[RPB];
    __shared__ int nxt[RPB];
    __shared__ int wsum[4];
    const int b = blockIdx.x;
    const int t = threadIdx.x;
    const int bstart = bbase[b], bend = bbase[b + 1];
    const int row0 = b << RPB_BITS;
    for (int i = t; i < RPB; i += 256) cnt[i] = 0;
    __syncthreads();
    for (int j = bstart + t; j < bend; j += 256)
        atomicAdd(&cnt[(gbuf[j].x >> 17) & (RPB - 1)], 1);
    __syncthreads();
    const int c0 = cnt[2 * t], c1 = cnt[2 * t + 1];
    const int s = c0 + c1;
    int v = s;
    #pragma unroll
    for (int d = 1; d < 64; d <<= 1) {
        int u = __shfl_up(v, (unsigned)d, 64);
        if ((t & 63) >= d) v += u;
    }
    if ((t & 63) == 63) wsum[t >> 6] = v;
    __syncthreads();
    int off = 0;
    #pragma unroll
    for (int i = 0; i < 4; ++i) if (i < (t >> 6)) off += wsum[i];
    const int e0 = off + v - s;
    nxt[2 * t]     = e0;
    nxt[2 * t + 1] = e0 + c0;
    const int r0 = row0 + 2 * t, r1 = row0 + 2 * t + 1;
    if (r0 < N) rowptr[r0] = bstart + e0;
    if (r1 < N) rowptr[r1] = bstart + e0 + c0;
    __syncthreads();
    for (int j = bstart + t; j < bend; j += 256) {
        const int2 p = gbuf[j];
        const int lr = (p.x >> 17) & (RPB - 1);
        const int pos = atomicAdd(&nxt[lr], 1);
        ecv[bstart + pos] = make_int2(p.x & 0x1FFFF, p.y);
    }
}

// ---------------------------------------------------------------- pass 1
__global__ __launch_bounds__(256) void pass1_kernel(
    const int* __restrict__ rowptr, const int2* __restrict__ ecv,
    const uint* __restrict__ H2,
    const float* __restrict__ b0, const float* __restrict__ fc0,
    const float* __restrict__ bf0,
    float* __restrict__ out, ushort* __restrict__ T16,
    float* __restrict__ dg1, int N) {
    int r = blockIdx.x * 4 + (threadIdx.x >> 6);
    r = __builtin_amdgcn_readfirstlane(r);
    if (r >= N) return;
    const int f = threadIdx.x & 63;
    const int jb = rowptr[r], je = rowptr[r + 1];
    float s0a = 0.f, s0b = 0.f, s0c = 0.f, s0d = 0.f;
    float s1a = 0.f, s1b = 0.f, s1c = 0.f, s1d = 0.f;
    float da = 0.f, db = 0.f;
    int j = jb;
    for (; j + 4 <= je; j += 4) {
        const int2 e0 = ecv[j], e1 = ecv[j + 1], e2 = ecv[j + 2], e3 = ecv[j + 3];
        const uint h0 = H2[(size_t)e0.x * F_HOP + f];
        const uint h1 = H2[(size_t)e1.x * F_HOP + f];
        const uint h2 = H2[(size_t)e2.x * F_HOP + f];
        const uint h3 = H2[(size_t)e3.x * F_HOP + f];
        const float v0 = __int_as_float(e0.y), v1 = __int_as_float(e1.y);
        const float v2 = __int_as_float(e2.y), v3 = __int_as_float(e3.y);
        da += v0 + v1; db += v2 + v3;
        s0a = fmaf(v0, bf_lo(h0), s0a); s1a = fmaf(v0, bf_hi(h0), s1a);
        s0b = fmaf(v1, bf_lo(h1), s0b); s1b = fmaf(v1, bf_hi(h1), s1b);
        s0c = fmaf(v2, bf_lo(h2), s0c); s1c = fmaf(v2, bf_hi(h2), s1c);
        s0d = fmaf(v3, bf_lo(h3), s0d); s1d = fmaf(v3, bf_hi(h3), s1d);
    }
    for (; j < je; ++j) {
        const int2 e0 = ecv[j];
        const uint h0 = H2[(size_t)e0.x * F_HOP + f];
        const float v0 = __int_as_float(e0.y);
        da += v0;
        s0a = fmaf(v0, bf_lo(h0), s0a); s1a = fmaf(v0, bf_hi(h0), s1a);
    }
    const float acc0 = (s0a + s0b) + (s0c + s0d);
    const float acc1 = (s1a + s1b) + (s1c + s1d);
    const float d = (da + db);
    T16[(size_t)r * F_HOP + f] = to_bf16(acc1);
    if (f == 0) dg1[r] = d;
    float y = (d > 0.f ? acc0 / d : 0.f) + b0[f];
    float t = y * fc0[f];
    #pragma unroll
    for (int m = 1; m < 64; m <<= 1) t += __shfl_xor(t, m, 64);
    const float g = 1.f / (1.f + __expf(-(t + bf0[0])));
    out[(size_t)r * F_ALL + f] = fmaxf(y, 0.f) + g * fminf(y, 0.f);
}

// ---------------------------------------------------------------- pass 2
__global__ __launch_bounds__(256) void pass2_kernel(
    const int* __restrict__ rowptr, const int2* __restrict__ ecv,
    const ushort* __restrict__ T16, const float* __restrict__ dg1,
    const float* __restrict__ b1, const float* __restrict__ fc1,
    const float* __restrict__ bf1,
    float* __restrict__ out, int N) {
    int r = blockIdx.x * 4 + (threadIdx.x >> 6);
    r = __builtin_amdgcn_readfirstlane(r);
    if (r >= N) return;
    const int f = threadIdx.x & 63;
    const int jb = rowptr[r], je = rowptr[r + 1];
    float sa = 0.f, sb = 0.f, sc = 0.f, sd = 0.f;
    float da = 0.f, db = 0.f;
    int j = jb;
    for (; j + 4 <= je; j += 4) {
        const int2 e0 = ecv[j], e1 = ecv[j + 1], e2 = ecv[j + 2], e3 = ecv[j + 3];
        const ushort t0 = T16[(size_t)e0.x * F_HOP + f];
        const ushort t1 = T16[(size_t)e1.x * F_HOP + f];
        const ushort t2 = T16[(size_t)e2.x * F_HOP + f];
        const ushort t3 = T16[(size_t)e3.x * F_HOP + f];
        const float g0 = dg1[e0.x], g1 = dg1[e1.x], g2 = dg1[e2.x], g3 = dg1[e3.x];
        const float v0 = __int_as_float(e0.y), v1 = __int_as_float(e1.y);
        const float v2 = __int_as_float(e2.y), v3 = __int_as_float(e3.y);
        da = fmaf(v0, g0, da); db = fmaf(v1, g1, db);
        da = fmaf(v2, g2, da); db = fmaf(v3, g3, db);
        sa = fmaf(v0, __uint_as_float((uint)t0 << 16), sa);
        sb = fmaf(v1, __uint_as_float((uint)t1 << 16), sb);
        sc = fmaf(v2, __uint_as_float((uint)t2 << 16), sc);
        sd = fmaf(v3, __uint_as_float((uint)t3 << 16), sd);
    }
    for (; j < je; ++j) {
        const int2 e0 = ecv[j];
        const ushort t0 = T16[(size_t)e0.x * F_HOP + f];
        const float v0 = __int_as_float(e0.y);
        da = fmaf(v0, dg1[e0.x], da);
        sa = fmaf(v0, __uint_as_float((uint)t0 << 16), sa);
    }
    const float acc = (sa + sb) + (sc + sd);
    const float d2 = da + db;
    float y = (d2 > 0.f ? acc / d2 : 0.f) + b1[f];
    float t = y * fc1[f];
    #pragma unroll
    for (int m = 1; m < 64; m <<= 1) t += __shfl_xor(t, m, 64);
    const float g = 1.f / (1.f + __expf(-(t + bf1[0])));
    out[(size_t)r * F_ALL + F_HOP + f] = fmaxf(y, 0.f) + g * fminf(y, 0.f);
}

// ---------------------------------------------------------------- launch
extern "C" void kernel_launch(void* const* d_in, const int* in_sizes, int n_in,
                              void* d_out, int out_size, void* d_ws, size_t ws_size,
                              hipStream_t stream) {
    const float* x   = (const float*)d_in[0];
    const int*   ei  = (const int*)  d_in[1];
    const float* ea  = (const float*)d_in[2];
    const float* W0  = (const float*)d_in[3];
    const float* b0  = (const float*)d_in[4];
    const float* W1  = (const float*)d_in[5];
    const float* b1  = (const float*)d_in[6];
    const float* fc0 = (const float*)d_in[7];
    const float* bf0 = (const float*)d_in[8];
    const float* fc1 = (const float*)d_in[9];
    const float* bf1 = (const float*)d_in[10];
    float* out = (float*)d_out;

    const int N = in_sizes[0] / F_IN;
    const int E = in_sizes[2];
    const int K = (N + RPB - 1) >> RPB_BITS;   // coarse buckets (<= KB_MAX)

    // workspace layout (4-byte units, regions 16B-aligned)
    uint*   H2   = (uint*)d_ws;                                  // N*64
    ushort* T16  = (ushort*)(H2 + (size_t)N * F_HOP);            // N*64 u16
    float*  dg1  = (float*)(T16 + (size_t)N * F_HOP);            // N
    int2*   gbuf = (int2*)(dg1 + (size_t)((N + 3) & ~3));        // E (bucketed edges)
    int2*   ecv  = gbuf + (size_t)E;                             // E (row-sorted edges)
    int*    bhist = (int*)(ecv + (size_t)E);                     // NBLK_HIST*KB_MAX
    int*    bbase = bhist + (size_t)NBLK_HIST * KB_MAX;          // K+1
    int*    gnext = bbase + (KB_MAX + 4);                        // K*16 (line-padded)
    int*    rowptr = gnext + KB_MAX * 16;                        // N+1

    gemm_mfma_kernel<<<(N + 63) / 64, 256, 0, stream>>>(x, W0, W1, H2, N);

    bucket_hist_kernel<<<NBLK_HIST, 256, 0, stream>>>(ei, bhist, E, K);
    bucket_scan_kernel<<<1, 256, 0, stream>>>(bhist, bbase, gnext, rowptr, E, K, N);
    append_kernel<<<(E + 255) / 256, 256, 0, stream>>>(ei, ea, gnext, gbuf, E);
    sort_kernel<<<K, 256, 0, stream>>>(bbase, gbuf, ecv, rowptr, N);

    pass1_kernel<<<(N + 3) / 4, 256, 0, stream>>>(
        rowptr, ecv, H2, b0, fc0, bf0, out, T16, dg1, N);

    pass2_kernel<<<(N + 3) / 4, 256, 0, stream>>>(
        rowptr, ecv, T16, dg1, b1, fc1, bf1, out, N);
}